// Round 2
// baseline (285.732 us; speedup 1.0000x reference)
//
#include <hip/hip_runtime.h>
#include <hip/hip_bf16.h>

typedef unsigned short u16;
typedef short s16x8 __attribute__((ext_vector_type(8)));
typedef short s16x4 __attribute__((ext_vector_type(4)));
typedef float f32x4 __attribute__((ext_vector_type(4)));

#define MFMA_BF16(a, b, c) __builtin_amdgcn_mfma_f32_16x16x32_bf16((a), (b), (c), 0, 0, 0)

static constexpr int D_IN   = 64;
static constexpr int H_DIM  = 512;
static constexpr int M_TILE = 64;
// AST=516: row stride 258 dwords == 2 mod 32 -> epilogue's 4 q-row groups land
// at bank offsets {0,8,16,24} -> scalar u16 writes are bank-conflict-free.
// (520 gave 16q mod 32 = {0,16,0,16}: q/q+2 same-bank 2-4 way serialization,
// 9.17M conflict cycles/dispatch = ~9% of runtime.) Rows now only 8B-aligned,
// so A-fragment loads use 2x ds_read_b64 instead of ds_read_b128 (same 12-cyc
// throughput class, milder conflict pattern).
static constexpr int AST    = 516;
static constexpr int XST    = 72;   // LDS row stride for x tile (16B-aligned rows)

__device__ __forceinline__ u16 f2bf(float f) {
  unsigned u = __builtin_bit_cast(unsigned, f);
  u += 0x7fffu + ((u >> 16) & 1u);   // RNE
  return (u16)(u >> 16);
}
__device__ __forceinline__ float bfb2f(unsigned bits16) {
  return __builtin_bit_cast(float, bits16 << 16);
}
__device__ __forceinline__ float fast_tanh(float x) {
  float e = __expf(2.0f * x);
  return 1.0f - 2.0f * __builtin_amdgcn_rcpf(e + 1.0f);
}
// Packed f32->bf16x2 (RNE, same rounding as f2bf): 1 instr replaces ~9.
__device__ __forceinline__ unsigned cvt_pk_bf16(float lo, float hi) {
  unsigned r;
  asm("v_cvt_pk_bf16_f32 %0, %1, %2" : "=v"(r) : "v"(lo), "v"(hi));
  return r;
}
// A-fragment load from 8B-aligned LDS row (AST=516): two ds_read_b64.
__device__ __forceinline__ s16x8 ld_a8(const u16* p) {
  s16x4 lo = *(const s16x4*)(p);
  s16x4 hi = *(const s16x4*)(p + 4);
  return __builtin_shufflevector(lo, hi, 0, 1, 2, 3, 4, 5, 6, 7);
}

// ---- prep: fp32 weights -> bf16, packed in MFMA-B-fragment order ----
// (unchanged; ~few us, not on critical path — the dur_us-vs-kernel gap proved
// to be harness overhead, not prep time)
__global__ __launch_bounds__(256) void prep_weights(const float* __restrict__ W0,
                                                    const float* __restrict__ W1,
                                                    const float* __restrict__ W2,
                                                    u16* __restrict__ ws) {
  u16* p0f = ws;                       // fwd W0: K=64,  N=512
  u16* p0b = p0f + D_IN * H_DIM;       // bwd W0^T: K=512, N=64
  u16* p1f = p0b + D_IN * H_DIM;
  u16* p1b = p1f + H_DIM * H_DIM;
  u16* p2f = p1b + H_DIM * H_DIM;
  u16* p2b = p2f + H_DIM * H_DIM;

  __shared__ __align__(16) u16 tile[64 * 72];   // 9.0 KB, stride 72 u16 (144B)

  int b = blockIdx.x;
  const float* src;
  u16 *dstf, *dstb;
  int rb, cb;
  bool isW0;
  if (b < 64) {
    src = W1; dstf = p1f; dstb = p1b; rb = b >> 3; cb = b & 7; isW0 = false;
  } else if (b < 128) {
    src = W2; dstf = p2f; dstb = p2b; rb = (b - 64) >> 3; cb = (b - 64) & 7; isW0 = false;
  } else {
    src = W0; dstf = p0f; dstb = p0b; rb = 0; cb = b - 128; isW0 = true;
  }

  const int tid = threadIdx.x;

  // ---- stage 64x64 fp32 tile -> bf16 LDS (coalesced: 4x float4 per thread) ----
  {
    int r = tid >> 2, cc = (tid & 3) * 16;
    const float4* s4 = (const float4*)(src + (size_t)(rb * 64 + r) * 512 + cb * 64 + cc);
    unsigned pk[8];
    #pragma unroll
    for (int v = 0; v < 4; ++v) {
      float4 f = s4[v];
      pk[v * 2]     = (unsigned)f2bf(f.x) | ((unsigned)f2bf(f.y) << 16);
      pk[v * 2 + 1] = (unsigned)f2bf(f.z) | ((unsigned)f2bf(f.w) << 16);
    }
    uint4* d = (uint4*)(tile + r * 72 + cc);
    d[0] = make_uint4(pk[0], pk[1], pk[2], pk[3]);
    d[1] = make_uint4(pk[4], pk[5], pk[6], pk[7]);
  }
  __syncthreads();

  const int c   = tid >> 6;          // 0..3: which ntg within this tile
  const int kcl = (tid >> 5) & 1;    // which 32-wide K half of this tile
  const int ls  = (tid * 2) & 63;    // even lane-slot; this thread does ls, ls+1
  const int q   = ls >> 4;
  const int ln  = ls & 15;

  // ---- fwd pack ----
  {
    __align__(16) u16 o[16];
    #pragma unroll
    for (int half = 0; half < 2; ++half)
      #pragma unroll
      for (int j = 0; j < 8; ++j)
        o[half * 8 + j] = tile[(kcl * 32 + q * 8 + j) * 72 + c * 16 + ln + half];
    int ntg   = 4 * cb + c;
    int kc    = 2 * rb + kcl;
    int chunk = isW0 ? (ntg * 2 + kc) : (ntg * 16 + kc);
    u16* dp = dstf + ((size_t)chunk * 64 + ls) * 8;
    *(uint4*)dp       = *(const uint4*)o;
    *(uint4*)(dp + 8) = *(const uint4*)(o + 8);
  }

  // ---- bwd pack ----
  {
    const u16* rp = tile + (c * 16 + ln) * 72 + kcl * 32 + q * 8;
    s16x8 r0 = *(const s16x8*)rp;
    s16x8 r1 = *(const s16x8*)(rp + 72);
    int ntg = 4 * rb + c;
    int kc  = 2 * cb + kcl;
    u16* dp = dstb + ((size_t)(ntg * 16 + kc) * 64 + ls) * 8;
    *(s16x8*)dp       = r0;
    *(s16x8*)(dp + 8) = r1;
  }
}

// Load this wave's 4 B-tiles of k-chunk KC straight into VGPRs (BR[4]).
#define LOAD_B4(BP, KC, BR)                                                     \
  {                                                                             \
    const u16* _sr = (BP) + ((size_t)wave << 15) + ((KC) << 9) + lane * 8;      \
    _Pragma("unroll")                                                           \
    for (int s = 0; s < 4; ++s)                                                 \
      (BR)[s] = *(const s16x8*)(_sr + (s << 13));                               \
  }

// 512-wide GEMM K-loop: wave = 64 rows x 64 cols (4 m-tiles x 4 n-tiles).
// A from LDS buf (2x ds_read_b64 per fragment, AST=516); B all-register,
// double-buffered 2-deep.
#define GEMM512_REG(BP)                                                         \
  {                                                                             \
    _Pragma("unroll") for (int mt = 0; mt < 4; ++mt)                            \
      _Pragma("unroll") for (int nt = 0; nt < 4; ++nt)                          \
        acc[mt][nt] = (f32x4){0.f, 0.f, 0.f, 0.f};                              \
    for (int kc2 = 0; kc2 < 8; ++kc2) {                                         \
      const int e = kc2 * 2;                                                    \
      {                                                                         \
        s16x8 a[4];                                                             \
        _Pragma("unroll")                                                       \
        for (int mt = 0; mt < 4; ++mt)                                          \
          a[mt] = ld_a8(buf + (mt * 16 + ln) * AST + e * 32 + q * 8);           \
        _Pragma("unroll")                                                       \
        for (int nt = 0; nt < 4; ++nt)                                          \
          _Pragma("unroll")                                                     \
          for (int mt = 0; mt < 4; ++mt)                                        \
            acc[mt][nt] = MFMA_BF16(a[mt], bregA[nt], acc[mt][nt]);             \
        if (kc2 < 7) LOAD_B4(BP, e + 2, bregA);                                 \
      }                                                                         \
      const int o = e + 1;                                                      \
      {                                                                         \
        s16x8 a[4];                                                             \
        _Pragma("unroll")                                                       \
        for (int mt = 0; mt < 4; ++mt)                                          \
          a[mt] = ld_a8(buf + (mt * 16 + ln) * AST + o * 32 + q * 8);           \
        _Pragma("unroll")                                                       \
        for (int nt = 0; nt < 4; ++nt)                                          \
          _Pragma("unroll")                                                     \
          for (int mt = 0; mt < 4; ++mt)                                        \
            acc[mt][nt] = MFMA_BF16(a[mt], bregB[nt], acc[mt][nt]);             \
        if (kc2 < 7) LOAD_B4(BP, o + 2, bregB);                                 \
      }                                                                         \
    }                                                                           \
  }

__global__ __launch_bounds__(512, 2) void hnn_fused(
    const float* __restrict__ x,
    const float* __restrict__ bias0,
    const float* __restrict__ bias1,
    const float* __restrict__ bias2,
    const float* __restrict__ W3,
    const u16* __restrict__ ws,
    float* __restrict__ out)
{
  const u16* p0f = ws;
  const u16* p0b = p0f + D_IN * H_DIM;
  const u16* p1f = p0b + D_IN * H_DIM;
  const u16* p1b = p1f + H_DIM * H_DIM;
  const u16* p2f = p1b + H_DIM * H_DIM;
  const u16* p2b = p2f + H_DIM * H_DIM;

  __shared__ __align__(16) u16 xs[M_TILE * XST];    // 9.0 KB
  __shared__ __align__(16) u16 buf[M_TILE * AST];   // 64.5 KB (A activations)

  const int tid  = threadIdx.x;
  const int wave = tid >> 6;      // 0..7
  const int lane = tid & 63;
  const int ln   = lane & 15;
  const int q    = lane >> 4;
  const int nwb  = wave * 64;     // wave's 64-col slice
  const int row0 = blockIdx.x * M_TILE;

  // ---- stage x tile: 64x64 fp32 -> bf16 LDS (512 thr x 8 elems) ----
  {
    int r = tid >> 3, c = (tid & 7) * 8;
    const float4* src = (const float4*)(x + (size_t)(row0 + r) * D_IN + c);
    float4 f0 = src[0];
    float4 f1 = src[1];
    unsigned pk0 = cvt_pk_bf16(f0.x, f0.y);
    unsigned pk1 = cvt_pk_bf16(f0.z, f0.w);
    unsigned pk2 = cvt_pk_bf16(f1.x, f1.y);
    unsigned pk3 = cvt_pk_bf16(f1.z, f1.w);
    uint4* dst = (uint4*)(xs + r * XST + c);
    *dst = make_uint4(pk0, pk1, pk2, pk3);
  }
  __syncthreads();

  f32x4 acc[4][4];
  s16x8 bregA[4], bregB[4];   // register-B double buffer
  unsigned h0p[4][4][2];      // h0 bf16x2-packed, C-layout (for tanh' in bwd)
  unsigned h1p[4][4][2];
  float bias[4];

  // ================ GEMM0: z0 = x @ W0  (K=64, register-B) ================
  #pragma unroll
  for (int nt = 0; nt < 4; ++nt) bias[nt] = bias0[nwb + nt * 16 + ln];
  #pragma unroll
  for (int mt = 0; mt < 4; ++mt)
    #pragma unroll
    for (int nt = 0; nt < 4; ++nt) acc[mt][nt] = (f32x4){0.f, 0.f, 0.f, 0.f};
  {
    const u16* bpw0 = p0f + (wave << 12) + lane * 8;  // (wave*4 ntg) * 2 kc * 512
    #pragma unroll
    for (int kc = 0; kc < 2; ++kc) {
      s16x8 a[4];
      #pragma unroll
      for (int mt = 0; mt < 4; ++mt)
        a[mt] = *(const s16x8*)(xs + (mt * 16 + ln) * XST + kc * 32 + q * 8);
      #pragma unroll
      for (int nt = 0; nt < 4; ++nt) {
        s16x8 b = *(const s16x8*)(bpw0 + (nt << 10) + (kc << 9));
        #pragma unroll
        for (int mt = 0; mt < 4; ++mt)
          acc[mt][nt] = MFMA_BF16(a[mt], b, acc[mt][nt]);
      }
    }
  }
  LOAD_B4(p1f, 0, bregA);   // prefetch GEMM1 kc 0,1; overlaps epilogue VALU
  LOAD_B4(p1f, 1, bregB);
  // epilogue: h0 = tanh(z0+b0) -> regs (packed) + buf
  #pragma unroll
  for (int mt = 0; mt < 4; ++mt)
    #pragma unroll
    for (int nt = 0; nt < 4; ++nt) {
      int col = nwb + nt * 16 + ln;
      float t0 = fast_tanh(acc[mt][nt][0] + bias[nt]);
      float t1 = fast_tanh(acc[mt][nt][1] + bias[nt]);
      float t2 = fast_tanh(acc[mt][nt][2] + bias[nt]);
      float t3 = fast_tanh(acc[mt][nt][3] + bias[nt]);
      unsigned pk0 = cvt_pk_bf16(t0, t1);
      unsigned pk1 = cvt_pk_bf16(t2, t3);
      h0p[mt][nt][0] = pk0;
      h0p[mt][nt][1] = pk1;
      u16* bp = buf + (mt * 16 + q * 4) * AST + col;
      bp[0]       = (u16)pk0;
      bp[AST]     = (u16)(pk0 >> 16);
      bp[2 * AST] = (u16)pk1;
      bp[3 * AST] = (u16)(pk1 >> 16);
    }
  __syncthreads();

  // ================ GEMM1: z1 = h0 @ W1 ================
  #pragma unroll
  for (int nt = 0; nt < 4; ++nt) bias[nt] = bias1[nwb + nt * 16 + ln];
  GEMM512_REG(p1f);
  __syncthreads();          // all waves done reading h0 (buf)
  LOAD_B4(p2f, 0, bregA);   // prefetch GEMM2
  LOAD_B4(p2f, 1, bregB);
  #pragma unroll
  for (int mt = 0; mt < 4; ++mt)
    #pragma unroll
    for (int nt = 0; nt < 4; ++nt) {
      int col = nwb + nt * 16 + ln;
      float t0 = fast_tanh(acc[mt][nt][0] + bias[nt]);
      float t1 = fast_tanh(acc[mt][nt][1] + bias[nt]);
      float t2 = fast_tanh(acc[mt][nt][2] + bias[nt]);
      float t3 = fast_tanh(acc[mt][nt][3] + bias[nt]);
      unsigned pk0 = cvt_pk_bf16(t0, t1);
      unsigned pk1 = cvt_pk_bf16(t2, t3);
      h1p[mt][nt][0] = pk0;
      h1p[mt][nt][1] = pk1;
      u16* bp = buf + (mt * 16 + q * 4) * AST + col;
      bp[0]       = (u16)pk0;
      bp[AST]     = (u16)(pk0 >> 16);
      bp[2 * AST] = (u16)pk1;
      bp[3 * AST] = (u16)(pk1 >> 16);
    }
  __syncthreads();

  // ================ GEMM2: z2 = h1 @ W2 ; gz2 = W3*(1-h2^2) ================
  #pragma unroll
  for (int nt = 0; nt < 4; ++nt) bias[nt] = bias2[nwb + nt * 16 + ln];
  float w3v[4];
  #pragma unroll
  for (int nt = 0; nt < 4; ++nt) w3v[nt] = W3[nwb + nt * 16 + ln];
  GEMM512_REG(p2f);
  __syncthreads();
  LOAD_B4(p2b, 0, bregA);   // prefetch GEMM3
  LOAD_B4(p2b, 1, bregB);
  #pragma unroll
  for (int mt = 0; mt < 4; ++mt)
    #pragma unroll
    for (int nt = 0; nt < 4; ++nt) {
      int col = nwb + nt * 16 + ln;
      float g[4];
      #pragma unroll
      for (int r = 0; r < 4; ++r) {
        float th = fast_tanh(acc[mt][nt][r] + bias[nt]);
        g[r] = w3v[nt] * (1.0f - th * th);
      }
      unsigned pk0 = cvt_pk_bf16(g[0], g[1]);
      unsigned pk1 = cvt_pk_bf16(g[2], g[3]);
      u16* bp = buf + (mt * 16 + q * 4) * AST + col;
      bp[0]       = (u16)pk0;
      bp[AST]     = (u16)(pk0 >> 16);
      bp[2 * AST] = (u16)pk1;
      bp[3 * AST] = (u16)(pk1 >> 16);
    }
  __syncthreads();

  // ================ GEMM3: g1 = gz2 @ W2^T ; gz1 = g1*(1-h1^2) ================
  GEMM512_REG(p2b);
  __syncthreads();
  LOAD_B4(p1b, 0, bregA);   // prefetch GEMM4
  LOAD_B4(p1b, 1, bregB);
  #pragma unroll
  for (int mt = 0; mt < 4; ++mt)
    #pragma unroll
    for (int nt = 0; nt < 4; ++nt) {
      int col = nwb + nt * 16 + ln;
      unsigned pa = h1p[mt][nt][0], pb = h1p[mt][nt][1];
      float hh[4] = { bfb2f(pa & 0xffffu), bfb2f(pa >> 16),
                      bfb2f(pb & 0xffffu), bfb2f(pb >> 16) };
      float g[4];
      #pragma unroll
      for (int r = 0; r < 4; ++r)
        g[r] = acc[mt][nt][r] * (1.0f - hh[r] * hh[r]);
      unsigned pk0 = cvt_pk_bf16(g[0], g[1]);
      unsigned pk1 = cvt_pk_bf16(g[2], g[3]);
      u16* bp = buf + (mt * 16 + q * 4) * AST + col;
      bp[0]       = (u16)pk0;
      bp[AST]     = (u16)(pk0 >> 16);
      bp[2 * AST] = (u16)pk1;
      bp[3 * AST] = (u16)(pk1 >> 16);
    }
  __syncthreads();

  // ================ GEMM4: g0 = gz1 @ W1^T ; gz0 = g0*(1-h0^2) ================
  GEMM512_REG(p1b);
  __syncthreads();
  #pragma unroll
  for (int mt = 0; mt < 4; ++mt)
    #pragma unroll
    for (int nt = 0; nt < 4; ++nt) {
      int col = nwb + nt * 16 + ln;
      unsigned pa = h0p[mt][nt][0], pb = h0p[mt][nt][1];
      float hh[4] = { bfb2f(pa & 0xffffu), bfb2f(pa >> 16),
                      bfb2f(pb & 0xffffu), bfb2f(pb >> 16) };
      float g[4];
      #pragma unroll
      for (int r = 0; r < 4; ++r)
        g[r] = acc[mt][nt][r] * (1.0f - hh[r] * hh[r]);
      unsigned pk0 = cvt_pk_bf16(g[0], g[1]);
      unsigned pk1 = cvt_pk_bf16(g[2], g[3]);
      u16* bp = buf + (mt * 16 + q * 4) * AST + col;
      bp[0]       = (u16)pk0;
      bp[AST]     = (u16)(pk0 >> 16);
      bp[2 * AST] = (u16)pk1;
      bp[3 * AST] = (u16)(pk1 >> 16);
    }
  __syncthreads();

  // ================ GEMM5: gradH = gz0 @ W0^T (64x64), symplectic store ======
  {
    f32x4 acc5[2];
    acc5[0] = (f32x4){0.f, 0.f, 0.f, 0.f};
    acc5[1] = (f32x4){0.f, 0.f, 0.f, 0.f};
    const int mt5 = wave & 3;                  // row tile 0..3
    const int nb5 = (wave >> 2) * 32;          // gradH column base (0 or 32)
    const u16* bp5 = p0b + ((wave >> 2) << 14) + lane * 8;  // ntg5*16kc*512
    #pragma unroll 2
    for (int kc = 0; kc < 16; ++kc) {
      s16x8 a = ld_a8(buf + (mt5 * 16 + ln) * AST + kc * 32 + q * 8);
      #pragma unroll
      for (int nt = 0; nt < 2; ++nt) {
        s16x8 b = *(const s16x8*)(bp5 + (nt << 13) + (kc << 9));
        acc5[nt] = MFMA_BF16(a, b, acc5[nt]);
      }
    }
    #pragma unroll
    for (int nt = 0; nt < 2; ++nt) {
      int g = nb5 + nt * 16 + ln;                 // gradH column
      int c = (g < 32) ? g + 32 : g - 32;         // out = concat(gradH[:,32:], -gradH[:,:32])
      float s = (g < 32) ? -1.0f : 1.0f;
      #pragma unroll
      for (int r = 0; r < 4; ++r) {
        int grow = row0 + mt5 * 16 + q * 4 + r;
        out[(size_t)grow * 64 + c] = s * acc5[nt][r];
      }
    }
  }
}

extern "C" void kernel_launch(void* const* d_in, const int* in_sizes, int n_in,
                              void* d_out, int out_size, void* d_ws, size_t ws_size,
                              hipStream_t stream) {
  // setup_inputs order: t, x, W0, b0, W1, b1, W2, b2, W3, b3
  const float* x  = (const float*)d_in[1];
  const float* W0 = (const float*)d_in[2];
  const float* b0 = (const float*)d_in[3];
  const float* W1 = (const float*)d_in[4];
  const float* b1 = (const float*)d_in[5];
  const float* W2 = (const float*)d_in[6];
  const float* b2 = (const float*)d_in[7];
  const float* W3 = (const float*)d_in[8];
  u16* ws = (u16*)d_ws;
  float* out = (float*)d_out;

  prep_weights<<<136, 256, 0, stream>>>(W0, W1, W2, ws);
  hnn_fused<<<65536 / M_TILE, 512, 0, stream>>>(x, b0, b1, b2, W3, ws, out);
}

// Round 3
// 240.477 us; speedup vs baseline: 1.1882x; 1.1882x over previous
//
#include <hip/hip_runtime.h>
#include <hip/hip_bf16.h>

typedef unsigned short u16;
typedef short s16x8 __attribute__((ext_vector_type(8)));
typedef float f32x4 __attribute__((ext_vector_type(4)));
typedef unsigned int u32x2 __attribute__((ext_vector_type(2)));

#define MFMA_BF16(a, b, c) __builtin_amdgcn_mfma_f32_16x16x32_bf16((a), (b), (c), 0, 0, 0)

static constexpr int D_IN   = 64;
static constexpr int H_DIM  = 512;
static constexpr int M_TILE = 64;
static constexpr int AST    = 520;  // row stride (bf16). b128 frag reads at 4(ln+q)%32
                                    // = 8 lanes x 4 dwords / 4-bank window = b128 minimum
                                    // -> conflict-free. (Round-2 AST=516+b64 regressed.)
static constexpr int XST    = 72;   // x-tile row stride (144B rows, 16B-aligned)

__device__ __forceinline__ u16 f2bf(float f) {
  unsigned u = __builtin_bit_cast(unsigned, f);
  u += 0x7fffu + ((u >> 16) & 1u);   // RNE
  return (u16)(u >> 16);
}
__device__ __forceinline__ float bfb2f(unsigned bits16) {
  return __builtin_bit_cast(float, bits16 << 16);
}
__device__ __forceinline__ float fast_tanh(float x) {
  float e = __expf(2.0f * x);
  return 1.0f - 2.0f * __builtin_amdgcn_rcpf(e + 1.0f);
}
// Packed f32->bf16x2 (RNE, same rounding as f2bf).
__device__ __forceinline__ unsigned cvt_pk_bf16(float lo, float hi) {
  unsigned r;
  asm("v_cvt_pk_bf16_f32 %0, %1, %2" : "=v"(r) : "v"(lo), "v"(hi));
  return r;
}

// ---- prep: fp32 weights -> bf16, packed in MFMA fragment order ----
// Packed as B-fragments of W (elem j -> W[k=kc*32+q*8+j][n=ntg*16+ln]).
// The SAME bytes reinterpret as A-fragments of W^T (A/B HW layouts are mutual
// transposes), which is how hnn_fused now consumes them (operand-swapped GEMM).
__global__ __launch_bounds__(256) void prep_weights(const float* __restrict__ W0,
                                                    const float* __restrict__ W1,
                                                    const float* __restrict__ W2,
                                                    u16* __restrict__ ws) {
  u16* p0f = ws;                       // W0 pack:   A-interp = W0^T  (fwd)
  u16* p0b = p0f + D_IN * H_DIM;       // W0^T pack: A-interp = W0    (bwd)
  u16* p1f = p0b + D_IN * H_DIM;
  u16* p1b = p1f + H_DIM * H_DIM;
  u16* p2f = p1b + H_DIM * H_DIM;
  u16* p2b = p2f + H_DIM * H_DIM;

  __shared__ __align__(16) u16 tile[64 * 72];   // 9.0 KB, stride 72 u16 (144B)

  int b = blockIdx.x;
  const float* src;
  u16 *dstf, *dstb;
  int rb, cb;
  bool isW0;
  if (b < 64) {
    src = W1; dstf = p1f; dstb = p1b; rb = b >> 3; cb = b & 7; isW0 = false;
  } else if (b < 128) {
    src = W2; dstf = p2f; dstb = p2b; rb = (b - 64) >> 3; cb = (b - 64) & 7; isW0 = false;
  } else {
    src = W0; dstf = p0f; dstb = p0b; rb = 0; cb = b - 128; isW0 = true;
  }

  const int tid = threadIdx.x;

  // ---- stage 64x64 fp32 tile -> bf16 LDS (coalesced: 4x float4 per thread) ----
  {
    int r = tid >> 2, cc = (tid & 3) * 16;
    const float4* s4 = (const float4*)(src + (size_t)(rb * 64 + r) * 512 + cb * 64 + cc);
    unsigned pk[8];
    #pragma unroll
    for (int v = 0; v < 4; ++v) {
      float4 f = s4[v];
      pk[v * 2]     = (unsigned)f2bf(f.x) | ((unsigned)f2bf(f.y) << 16);
      pk[v * 2 + 1] = (unsigned)f2bf(f.z) | ((unsigned)f2bf(f.w) << 16);
    }
    uint4* d = (uint4*)(tile + r * 72 + cc);
    d[0] = make_uint4(pk[0], pk[1], pk[2], pk[3]);
    d[1] = make_uint4(pk[4], pk[5], pk[6], pk[7]);
  }
  __syncthreads();

  const int c   = tid >> 6;          // 0..3: which ntg within this tile
  const int kcl = (tid >> 5) & 1;    // which 32-wide K half of this tile
  const int ls  = (tid * 2) & 63;    // even lane-slot; this thread does ls, ls+1
  const int q   = ls >> 4;
  const int ln  = ls & 15;

  // ---- fwd pack ----
  {
    __align__(16) u16 o[16];
    #pragma unroll
    for (int half = 0; half < 2; ++half)
      #pragma unroll
      for (int j = 0; j < 8; ++j)
        o[half * 8 + j] = tile[(kcl * 32 + q * 8 + j) * 72 + c * 16 + ln + half];
    int ntg   = 4 * cb + c;
    int kc    = 2 * rb + kcl;
    int chunk = isW0 ? (ntg * 2 + kc) : (ntg * 16 + kc);
    u16* dp = dstf + ((size_t)chunk * 64 + ls) * 8;
    *(uint4*)dp       = *(const uint4*)o;
    *(uint4*)(dp + 8) = *(const uint4*)(o + 8);
  }

  // ---- bwd pack ----
  {
    const u16* rp = tile + (c * 16 + ln) * 72 + kcl * 32 + q * 8;
    s16x8 r0 = *(const s16x8*)rp;
    s16x8 r1 = *(const s16x8*)(rp + 72);
    int ntg = 4 * rb + c;
    int kc  = 2 * cb + kcl;
    u16* dp = dstb + ((size_t)(ntg * 16 + kc) * 64 + ls) * 8;
    *(s16x8*)dp       = r0;
    *(s16x8*)(dp + 8) = r1;
  }
}

// Load this wave's 4 weight A-fragments (feature tiles ft=0..3) of k-chunk KC
// straight into VGPRs. Contiguous 1KB per wave, L2-resident.
#define LOAD_B4(BP, KC, BR)                                                     \
  {                                                                             \
    const u16* _sr = (BP) + ((size_t)wave << 15) + ((KC) << 9) + lane * 8;      \
    _Pragma("unroll")                                                           \
    for (int s = 0; s < 4; ++s)                                                 \
      (BR)[s] = *(const s16x8*)(_sr + (s << 13));                               \
  }

// Operand-swapped 512-wide GEMM: computes Z^T = W^T . act^T for this wave's
// 64-feature slice x 64 batch. A = weight frags (registers, double-buffered
// 2-deep); B = activation frags from LDS buf (b128, conflict-free).
// acc[ft][bt] reg r = Z[batch=bt*16+ln][feature=nwb+ft*16+q*4+r]:
// thread holds 4 CONSECUTIVE features of one batch row -> 8B epilogue writes.
#define GEMM512_REG(BP)                                                         \
  {                                                                             \
    _Pragma("unroll") for (int ft = 0; ft < 4; ++ft)                            \
      _Pragma("unroll") for (int bt = 0; bt < 4; ++bt)                          \
        acc[ft][bt] = (f32x4){0.f, 0.f, 0.f, 0.f};                              \
    for (int kc2 = 0; kc2 < 8; ++kc2) {                                         \
      const int e = kc2 * 2;                                                    \
      {                                                                         \
        s16x8 a[4];                                                             \
        _Pragma("unroll")                                                       \
        for (int bt = 0; bt < 4; ++bt)                                          \
          a[bt] = *(const s16x8*)(buf + (bt * 16 + ln) * AST + e * 32 + q * 8); \
        _Pragma("unroll")                                                       \
        for (int ft = 0; ft < 4; ++ft)                                          \
          _Pragma("unroll")                                                     \
          for (int bt = 0; bt < 4; ++bt)                                        \
            acc[ft][bt] = MFMA_BF16(bregA[ft], a[bt], acc[ft][bt]);             \
        if (kc2 < 7) LOAD_B4(BP, e + 2, bregA);                                 \
      }                                                                         \
      const int o = e + 1;                                                      \
      {                                                                         \
        s16x8 a[4];                                                             \
        _Pragma("unroll")                                                       \
        for (int bt = 0; bt < 4; ++bt)                                          \
          a[bt] = *(const s16x8*)(buf + (bt * 16 + ln) * AST + o * 32 + q * 8); \
        _Pragma("unroll")                                                       \
        for (int ft = 0; ft < 4; ++ft)                                          \
          _Pragma("unroll")                                                     \
          for (int bt = 0; bt < 4; ++bt)                                        \
            acc[ft][bt] = MFMA_BF16(bregB[ft], a[bt], acc[ft][bt]);             \
        if (kc2 < 7) LOAD_B4(BP, o + 2, bregB);                                 \
      }                                                                         \
    }                                                                           \
  }

__global__ __launch_bounds__(512, 2) void hnn_fused(
    const float* __restrict__ x,
    const float* __restrict__ bias0,
    const float* __restrict__ bias1,
    const float* __restrict__ bias2,
    const float* __restrict__ W3,
    const u16* __restrict__ ws,
    float* __restrict__ out)
{
  const u16* p0f = ws;
  const u16* p0b = p0f + D_IN * H_DIM;
  const u16* p1f = p0b + D_IN * H_DIM;
  const u16* p1b = p1f + H_DIM * H_DIM;
  const u16* p2f = p1b + H_DIM * H_DIM;
  const u16* p2b = p2f + H_DIM * H_DIM;

  __shared__ __align__(16) u16 xs[M_TILE * XST];    // 9.0 KB
  __shared__ __align__(16) u16 buf[M_TILE * AST];   // 65.0 KB (activations, [batch][feature])

  const int tid  = threadIdx.x;
  const int wave = tid >> 6;      // 0..7
  const int lane = tid & 63;
  const int ln   = lane & 15;
  const int q    = lane >> 4;
  const int nwb  = wave * 64;     // wave's 64-FEATURE slice base
  const int row0 = blockIdx.x * M_TILE;

  // ---- stage x tile: 64x64 fp32 -> bf16 LDS (512 thr x 8 elems) ----
  {
    int r = tid >> 3, c = (tid & 7) * 8;
    const float4* src = (const float4*)(x + (size_t)(row0 + r) * D_IN + c);
    float4 f0 = src[0];
    float4 f1 = src[1];
    unsigned pk0 = cvt_pk_bf16(f0.x, f0.y);
    unsigned pk1 = cvt_pk_bf16(f0.z, f0.w);
    unsigned pk2 = cvt_pk_bf16(f1.x, f1.y);
    unsigned pk3 = cvt_pk_bf16(f1.z, f1.w);
    uint4* dst = (uint4*)(xs + r * XST + c);
    *dst = make_uint4(pk0, pk1, pk2, pk3);
  }
  __syncthreads();

  f32x4 acc[4][4];
  s16x8 bregA[4], bregB[4];   // weight A-fragment double buffer
  unsigned h0p[4][4][2];      // h0 bf16x2-packed per (ft,bt): 4 consecutive features
  unsigned h1p[4][4][2];

  // ================ GEMM0: z0^T = W0^T . x^T  (K=64) ================
  #pragma unroll
  for (int ft = 0; ft < 4; ++ft)
    #pragma unroll
    for (int bt = 0; bt < 4; ++bt) acc[ft][bt] = (f32x4){0.f, 0.f, 0.f, 0.f};
  {
    const u16* bpw0 = p0f + (wave << 12) + lane * 8;  // (wave*4+ft)*2kc chunks
    #pragma unroll
    for (int kc = 0; kc < 2; ++kc) {
      s16x8 a[4];
      #pragma unroll
      for (int bt = 0; bt < 4; ++bt)
        a[bt] = *(const s16x8*)(xs + (bt * 16 + ln) * XST + kc * 32 + q * 8);
      #pragma unroll
      for (int ft = 0; ft < 4; ++ft) {
        s16x8 w = *(const s16x8*)(bpw0 + (ft << 10) + (kc << 9));
        #pragma unroll
        for (int bt = 0; bt < 4; ++bt)
          acc[ft][bt] = MFMA_BF16(w, a[bt], acc[ft][bt]);
      }
    }
  }
  LOAD_B4(p1f, 0, bregA);   // prefetch GEMM1 kc 0,1; overlaps epilogue VALU
  LOAD_B4(p1f, 1, bregB);
  // epilogue: h0 = tanh(z0+b0) -> regs (packed) + buf[batch][feature], 8B writes
  {
    f32x4 b4[4];
    #pragma unroll
    for (int ft = 0; ft < 4; ++ft)
      b4[ft] = *(const f32x4*)(bias0 + nwb + ft * 16 + q * 4);
    #pragma unroll
    for (int ft = 0; ft < 4; ++ft)
      #pragma unroll
      for (int bt = 0; bt < 4; ++bt) {
        float t0 = fast_tanh(acc[ft][bt][0] + b4[ft][0]);
        float t1 = fast_tanh(acc[ft][bt][1] + b4[ft][1]);
        float t2 = fast_tanh(acc[ft][bt][2] + b4[ft][2]);
        float t3 = fast_tanh(acc[ft][bt][3] + b4[ft][3]);
        unsigned pk0 = cvt_pk_bf16(t0, t1);
        unsigned pk1 = cvt_pk_bf16(t2, t3);
        h0p[ft][bt][0] = pk0;
        h0p[ft][bt][1] = pk1;
        *(u32x2*)(buf + (bt * 16 + ln) * AST + nwb + ft * 16 + q * 4) = (u32x2){pk0, pk1};
      }
  }
  __syncthreads();

  // ================ GEMM1: z1^T = W1^T . h0^T ================
  GEMM512_REG(p1f);
  __syncthreads();          // all waves done reading h0 (buf)
  LOAD_B4(p2f, 0, bregA);   // prefetch GEMM2
  LOAD_B4(p2f, 1, bregB);
  {
    f32x4 b4[4];
    #pragma unroll
    for (int ft = 0; ft < 4; ++ft)
      b4[ft] = *(const f32x4*)(bias1 + nwb + ft * 16 + q * 4);
    #pragma unroll
    for (int ft = 0; ft < 4; ++ft)
      #pragma unroll
      for (int bt = 0; bt < 4; ++bt) {
        float t0 = fast_tanh(acc[ft][bt][0] + b4[ft][0]);
        float t1 = fast_tanh(acc[ft][bt][1] + b4[ft][1]);
        float t2 = fast_tanh(acc[ft][bt][2] + b4[ft][2]);
        float t3 = fast_tanh(acc[ft][bt][3] + b4[ft][3]);
        unsigned pk0 = cvt_pk_bf16(t0, t1);
        unsigned pk1 = cvt_pk_bf16(t2, t3);
        h1p[ft][bt][0] = pk0;
        h1p[ft][bt][1] = pk1;
        *(u32x2*)(buf + (bt * 16 + ln) * AST + nwb + ft * 16 + q * 4) = (u32x2){pk0, pk1};
      }
  }
  __syncthreads();

  // ================ GEMM2: z2^T = W2^T . h1^T ; gz2 = W3*(1-h2^2) ================
  GEMM512_REG(p2f);
  __syncthreads();
  LOAD_B4(p2b, 0, bregA);   // prefetch GEMM3
  LOAD_B4(p2b, 1, bregB);
  {
    f32x4 b4[4], w34[4];
    #pragma unroll
    for (int ft = 0; ft < 4; ++ft) {
      b4[ft]  = *(const f32x4*)(bias2 + nwb + ft * 16 + q * 4);
      w34[ft] = *(const f32x4*)(W3 + nwb + ft * 16 + q * 4);
    }
    #pragma unroll
    for (int ft = 0; ft < 4; ++ft)
      #pragma unroll
      for (int bt = 0; bt < 4; ++bt) {
        float g[4];
        #pragma unroll
        for (int r = 0; r < 4; ++r) {
          float th = fast_tanh(acc[ft][bt][r] + b4[ft][r]);
          g[r] = w34[ft][r] * (1.0f - th * th);
        }
        unsigned pk0 = cvt_pk_bf16(g[0], g[1]);
        unsigned pk1 = cvt_pk_bf16(g[2], g[3]);
        *(u32x2*)(buf + (bt * 16 + ln) * AST + nwb + ft * 16 + q * 4) = (u32x2){pk0, pk1};
      }
  }
  __syncthreads();

  // ================ GEMM3: g1^T = W2 . gz2^T ; gz1 = g1*(1-h1^2) ================
  GEMM512_REG(p2b);
  __syncthreads();
  LOAD_B4(p1b, 0, bregA);   // prefetch GEMM4
  LOAD_B4(p1b, 1, bregB);
  #pragma unroll
  for (int ft = 0; ft < 4; ++ft)
    #pragma unroll
    for (int bt = 0; bt < 4; ++bt) {
      unsigned pa = h1p[ft][bt][0], pb = h1p[ft][bt][1];
      float hh[4] = { bfb2f(pa & 0xffffu), bfb2f(pa >> 16),
                      bfb2f(pb & 0xffffu), bfb2f(pb >> 16) };
      float g[4];
      #pragma unroll
      for (int r = 0; r < 4; ++r)
        g[r] = acc[ft][bt][r] * (1.0f - hh[r] * hh[r]);
      unsigned pk0 = cvt_pk_bf16(g[0], g[1]);
      unsigned pk1 = cvt_pk_bf16(g[2], g[3]);
      *(u32x2*)(buf + (bt * 16 + ln) * AST + nwb + ft * 16 + q * 4) = (u32x2){pk0, pk1};
    }
  __syncthreads();

  // ================ GEMM4: g0^T = W1 . gz1^T ; gz0 = g0*(1-h0^2) ================
  GEMM512_REG(p1b);
  __syncthreads();
  #pragma unroll
  for (int ft = 0; ft < 4; ++ft)
    #pragma unroll
    for (int bt = 0; bt < 4; ++bt) {
      unsigned pa = h0p[ft][bt][0], pb = h0p[ft][bt][1];
      float hh[4] = { bfb2f(pa & 0xffffu), bfb2f(pa >> 16),
                      bfb2f(pb & 0xffffu), bfb2f(pb >> 16) };
      float g[4];
      #pragma unroll
      for (int r = 0; r < 4; ++r)
        g[r] = acc[ft][bt][r] * (1.0f - hh[r] * hh[r]);
      unsigned pk0 = cvt_pk_bf16(g[0], g[1]);
      unsigned pk1 = cvt_pk_bf16(g[2], g[3]);
      *(u32x2*)(buf + (bt * 16 + ln) * AST + nwb + ft * 16 + q * 4) = (u32x2){pk0, pk1};
    }
  __syncthreads();

  // ================ GEMM5: gradH^T = W0 . gz0^T (64x64), symplectic store =====
  // Wave: d-tile dt = wave&3, batch half bh = wave>>2 (2 batch tiles).
  // Thread holds 4 consecutive d's of one batch row -> float4 global store.
  {
    f32x4 acc5[2];
    acc5[0] = (f32x4){0.f, 0.f, 0.f, 0.f};
    acc5[1] = (f32x4){0.f, 0.f, 0.f, 0.f};
    const int dt = wave & 3;
    const int bh = wave >> 2;
    #pragma unroll 2
    for (int kc = 0; kc < 16; ++kc) {
      s16x8 aw = *(const s16x8*)(p0b + (size_t)((dt * 16 + kc) * 64 + lane) * 8);
      #pragma unroll
      for (int i = 0; i < 2; ++i) {
        s16x8 bx = *(const s16x8*)(buf + ((bh * 2 + i) * 16 + ln) * AST + kc * 32 + q * 8);
        acc5[i] = MFMA_BF16(aw, bx, acc5[i]);
      }
    }
    const int d0 = dt * 16 + q * 4;               // 4 consecutive d's, same 32-half
    const int c0 = (d0 < 32) ? d0 + 32 : d0 - 32; // out = concat(gradH[:,32:], -gradH[:,:32])
    const float s = (d0 < 32) ? -1.0f : 1.0f;
    #pragma unroll
    for (int i = 0; i < 2; ++i) {
      int brow = row0 + (bh * 2 + i) * 16 + ln;
      f32x4 v = { s * acc5[i][0], s * acc5[i][1], s * acc5[i][2], s * acc5[i][3] };
      *(f32x4*)(out + (size_t)brow * 64 + c0) = v;
    }
  }
}

extern "C" void kernel_launch(void* const* d_in, const int* in_sizes, int n_in,
                              void* d_out, int out_size, void* d_ws, size_t ws_size,
                              hipStream_t stream) {
  // setup_inputs order: t, x, W0, b0, W1, b1, W2, b2, W3, b3
  const float* x  = (const float*)d_in[1];
  const float* W0 = (const float*)d_in[2];
  const float* b0 = (const float*)d_in[3];
  const float* W1 = (const float*)d_in[4];
  const float* b1 = (const float*)d_in[5];
  const float* W2 = (const float*)d_in[6];
  const float* b2 = (const float*)d_in[7];
  const float* W3 = (const float*)d_in[8];
  u16* ws = (u16*)d_ws;
  float* out = (float*)d_out;

  prep_weights<<<136, 256, 0, stream>>>(W0, W1, W2, ws);
  hnn_fused<<<65536 / M_TILE, 512, 0, stream>>>(x, b0, b1, b2, W3, ws, out);
}